// Round 16
// baseline (810.273 us; speedup 1.0000x reference)
//
#include <hip/hip_runtime.h>
#include <hip/hip_bf16.h>

#define B_ 32
#define S_ 128
#define H_ 1024
#define V_ 32000

using short8 = __attribute__((ext_vector_type(8))) short;
using f32x4  = __attribute__((ext_vector_type(4))) float;
using u32x4  = __attribute__((ext_vector_type(4))) unsigned;
typedef unsigned short u16;

__device__ inline u16 f2bf(float f) {
  unsigned u = __float_as_uint(f);
  unsigned r = u + 0x7FFFu + ((u >> 16) & 1u);  // RNE
  return (u16)(r >> 16);
}
__device__ inline float bf2f(u16 h) { return __uint_as_float(((unsigned)h) << 16); }

__device__ inline void gload_lds16(const void* g, void* l) {
  __builtin_amdgcn_global_load_lds((const __attribute__((address_space(1))) unsigned int*)g,
                                   (__attribute__((address_space(3))) unsigned int*)l, 16, 0, 0);
}
// sc0|sc1 (CPol GLC|SCC = 17): bypass L1/L2, fetch from coherence point.
__device__ inline void gload_lds16_sc(const void* g, void* l) {
  __builtin_amdgcn_global_load_lds((const __attribute__((address_space(1))) unsigned int*)g,
                                   (__attribute__((address_space(3))) unsigned int*)l, 16, 0, 17);
}

// ---- A-frag layout: unit(kt, mt, l) = (kt*MT + mt)*64 + l ; 8 bf16 per unit ----
// element: row = mt*16 + (l&15), k = kt*32 + (l>>4)*8 + j
// ---- B-frag layout: unit(kt, nf, l) = (kt*NT + nf)*64 + l ----

// ---------- merged prep: all conversions in one launch (region-dispatched) ----------
__global__ void k_prep_all(const int* __restrict__ idx, const float* __restrict__ E,
                           u16* __restrict__ embf,
                           const float* __restrict__ Wxr, const float* __restrict__ Wxz,
                           const float* __restrict__ Wxg, u16* __restrict__ wxf,
                           const float* __restrict__ Whr, const float* __restrict__ Whz,
                           const float* __restrict__ Whg, u16* __restrict__ whh,
                           u16* __restrict__ whl,
                           const float* __restrict__ h0, unsigned* __restrict__ hpack,
                           int* __restrict__ sync,
                           const float* __restrict__ bxr, const float* __restrict__ bxz,
                           const float* __restrict__ bxg, float* __restrict__ bcat) {
  int gg = blockIdx.x * blockDim.x + threadIdx.x;
  if (gg < 524288) {
    int g = gg;
    int kt = g >> 14, rem = g & 16383, mt = rem >> 6, l = rem & 63;
    int row = mt * 16 + (l & 15);
    int k = kt * 32 + ((l >> 4) << 3);
    const float4* src = reinterpret_cast<const float4*>(E + (size_t)idx[row] * H_ + k);
    float4 a = src[0], b = src[1];
    u16 o[8] = {f2bf(a.x), f2bf(a.y), f2bf(a.z), f2bf(a.w),
                f2bf(b.x), f2bf(b.y), f2bf(b.z), f2bf(b.w)};
    *reinterpret_cast<uint4*>(embf + (size_t)g * 8) = *reinterpret_cast<const uint4*>(o);
  } else if (gg < 917504) {
    int g = gg - 524288;
    int kt = g / 12288, rem = g % 12288, nf = rem >> 6, l = rem & 63;
    int col = nf * 16 + (l & 15);
    int gate = col >> 10, j = col & 1023;
    int k0 = kt * 32 + ((l >> 4) << 3);
    const float* W = gate == 0 ? Wxr : (gate == 1 ? Wxz : Wxg);
    u16 o[8];
#pragma unroll
    for (int e = 0; e < 8; ++e) o[e] = f2bf(W[(size_t)(k0 + e) * H_ + j]);
    *reinterpret_cast<uint4*>(wxf + (size_t)g * 8) = *reinterpret_cast<const uint4*>(o);
  } else if (gg < 1310720) {
    int g = gg - 917504;
    int jtile = g / 6144, rem = g % 6144;
    int gate = rem >> 11, kt = (rem >> 6) & 31, l = rem & 63;
    int col = jtile * 16 + (l & 15);
    int k0 = kt * 32 + ((l >> 4) << 3);
    const float* W = gate == 0 ? Whr : (gate == 1 ? Whz : Whg);
    u16 oh[8], ol[8];
#pragma unroll
    for (int e = 0; e < 8; ++e) {
      float v = W[(size_t)(k0 + e) * H_ + col];
      u16 hi = f2bf(v);
      oh[e] = hi;
      ol[e] = f2bf(v - bf2f(hi));
    }
    *reinterpret_cast<uint4*>(whh + (size_t)g * 8) = *reinterpret_cast<const uint4*>(oh);
    *reinterpret_cast<uint4*>(whl + (size_t)g * 8) = *reinterpret_cast<const uint4*>(ol);
  } else if (gg < 1343488) {
    int i = gg - 1310720;
    float v = h0[i];
    u16 hi = f2bf(v);
    hpack[i] = (unsigned)hi | ((unsigned)f2bf(v - bf2f(hi)) << 16);
    if (i < 8192) sync[i] = 0;
  } else if (gg < 1346560) {
    int j = gg - 1343488;
    bcat[j] = j < 1024 ? bxr[j] : (j < 2048 ? bxz[j - 1024] : bxg[j - 2048]);
  }
}

// ---------- m97-style GEMM (xproj only): C[M][N] = A*B + bias ----------
template <int NTSTORE>
__launch_bounds__(256, 3)
__global__ void k_gemm_frag(const u16* __restrict__ Af, const u16* __restrict__ Bf,
                            const float* __restrict__ bias, float* __restrict__ C,
                            int MT, int NT, int KT, int N) {
  __shared__ __align__(16) u16 lA[2 * 512 * 8];
  __shared__ __align__(16) u16 lB[2 * 512 * 8];
  int tid = threadIdx.x, w = tid >> 6, lane = tid & 63;
  int mt0 = blockIdx.x * 8, nf0 = blockIdx.y * 8;
  int wm = (w >> 1) * 4, wn = (w & 1) * 4;
  f32x4 acc[4][4] = {};
  for (int kt = 0; kt < KT; kt += 2) {
    __syncthreads();
#pragma unroll
    for (int hh = 0; hh < 2; ++hh) {
      const u16* ga = Af + ((size_t)(kt + hh) * MT + mt0) * 512;
      const u16* gb = Bf + ((size_t)(kt + hh) * NT + nf0) * 512;
#pragma unroll
      for (int r = 0; r < 2; ++r) {
        int ub = (r * 4 + w) * 64;
        gload_lds16(ga + (size_t)(ub + lane) * 8, lA + (size_t)(hh * 512 + ub) * 8);
        gload_lds16(gb + (size_t)(ub + lane) * 8, lB + (size_t)(hh * 512 + ub) * 8);
      }
    }
    __syncthreads();
#pragma unroll
    for (int hh = 0; hh < 2; ++hh) {
      short8 af[4], bfr[4];
#pragma unroll
      for (int i = 0; i < 4; ++i) {
        af[i]  = *reinterpret_cast<const short8*>(lA + ((hh * 8 + wm + i) * 64 + lane) * 8);
        bfr[i] = *reinterpret_cast<const short8*>(lB + ((hh * 8 + wn + i) * 64 + lane) * 8);
      }
#pragma unroll
      for (int mi = 0; mi < 4; ++mi)
#pragma unroll
        for (int ni = 0; ni < 4; ++ni)
          acc[mi][ni] = __builtin_amdgcn_mfma_f32_16x16x32_bf16(af[mi], bfr[ni], acc[mi][ni], 0, 0, 0);
    }
  }
  int m0 = mt0 * 16, n0 = nf0 * 16;
#pragma unroll
  for (int ni = 0; ni < 4; ++ni) {
    int col = n0 + (wn + ni) * 16 + (lane & 15);
    float bv = bias[col];
#pragma unroll
    for (int mi = 0; mi < 4; ++mi) {
#pragma unroll
      for (int q = 0; q < 4; ++q) {
        int row = m0 + (wm + mi) * 16 + ((lane >> 4) << 2) + q;
        float v = acc[mi][ni][q] + bv;
        if (NTSTORE) __builtin_nontemporal_store(v, &C[(size_t)row * N + col]);
        else         C[(size_t)row * N + col] = v;
      }
    }
  }
}

// ---------- 256x256 8-phase-style pipelined GEMM (output GEMM) ----------
// 8 waves (2M x 4N), BK=64 (2 frag-kt), LDS dbuf split in 4 half-tiles
// {A-kth0, B-kth0, A-kth1, B-kth1}. 4 phases/K-tile: per phase 4-8 ds_read_b128,
// 2 gload_lds (next tile), counted vmcnt(4) at P1/P3 (never 0 mid-loop),
// raw s_barrier + lgkmcnt(0) + sched_barrier(0) + setprio around 16 MFMA.
__launch_bounds__(512, 2)
__global__ void k_gemm256p(const u16* __restrict__ Af, const u16* __restrict__ Bf,
                           const float* __restrict__ bias, float* __restrict__ C,
                           int MT, int NTt, int KT2, int N) {
  __shared__ __align__(16) u16 lA[2][2][16 * 512];  // [buf][kth] 16KB each
  __shared__ __align__(16) u16 lB[2][2][16 * 512];
  const int tid = threadIdx.x, w = tid >> 6, l = tid & 63;
  const int mt0 = blockIdx.x * 16, nf0 = blockIdx.y * 16;
  const int wm = (w & 1) * 8, wn = (w >> 1) * 4;  // wave: 8 mt x 4 nf = 128x64
  f32x4 acc[8][4] = {};

#define STG_A(buf_, t_, kth_) {                                                    \
    const u16* g0 = Af + ((size_t)(2 * (t_) + (kth_)) * MT + mt0) * 512;           \
    gload_lds16(g0 + (size_t)tid * 8,         &lA[buf_][kth_][(size_t)tid * 8]);   \
    gload_lds16(g0 + (size_t)(512 + tid) * 8, &lA[buf_][kth_][(size_t)(512 + tid) * 8]); }
#define STG_B(buf_, t_, kth_) {                                                    \
    const u16* g0 = Bf + ((size_t)(2 * (t_) + (kth_)) * NTt + nf0) * 512;          \
    gload_lds16(g0 + (size_t)tid * 8,         &lB[buf_][kth_][(size_t)tid * 8]);   \
    gload_lds16(g0 + (size_t)(512 + tid) * 8, &lB[buf_][kth_][(size_t)(512 + tid) * 8]); }

  // prologue: stage tile 0 fully; wait halves-0 (oldest 4 of 8), publish.
  STG_A(0, 0, 0); STG_B(0, 0, 0);
  STG_A(0, 0, 1); STG_B(0, 0, 1);
  asm volatile("s_waitcnt vmcnt(4)" ::: "memory");
  __builtin_amdgcn_s_barrier();

#define PHASE(kth_, mth_, STG_STMT, WAIT_STMT)                                     \
  {                                                                                \
    short8 afr[4];                                                                 \
    _Pragma("unroll") for (int i = 0; i < 4; ++i)                                  \
      afr[i] = *reinterpret_cast<const short8*>(                                   \
          &lA[cur][kth_][((size_t)(wm + (mth_) * 4 + i) * 64 + l) * 8]);           \
    if ((mth_) == 0) {                                                             \
      _Pragma("unroll") for (int i = 0; i < 4; ++i)                                \
        bfr[i] = *reinterpret_cast<const short8*>(                                 \
            &lB[cur][kth_][((size_t)(wn + i) * 64 + l) * 8]);                      \
    }                                                                              \
    STG_STMT;                                                                      \
    WAIT_STMT;                                                                     \
    __builtin_amdgcn_s_barrier();                                                  \
    asm volatile("s_waitcnt lgkmcnt(0)" ::: "memory");                             \
    __builtin_amdgcn_sched_barrier(0);                                             \
    __builtin_amdgcn_s_setprio(1);                                                 \
    _Pragma("unroll") for (int i = 0; i < 4; ++i)                                  \
      _Pragma("unroll") for (int j = 0; j < 4; ++j)                                \
        acc[(mth_) * 4 + i][j] = __builtin_amdgcn_mfma_f32_16x16x32_bf16(          \
            afr[i], bfr[j], acc[(mth_) * 4 + i][j], 0, 0, 0);                      \
    __builtin_amdgcn_s_setprio(0);                                                 \
    __builtin_amdgcn_s_barrier();                                                  \
  }

  for (int t = 0; t < KT2; ++t) {
    const int cur = t & 1, nxt = cur ^ 1;
    const bool last = (t == KT2 - 1);
    short8 bfr[4];
    // P0: kth0, mth0 — issue A0(t+1)
    PHASE(0, 0, if (!last) STG_A(nxt, t + 1, 0), );
    // P1: kth0, mth1 — issue B0(t+1); establish A1,B1 of t (oldest 4)
    PHASE(0, 1, if (!last) STG_B(nxt, t + 1, 0),
          if (!last) { asm volatile("s_waitcnt vmcnt(4)" ::: "memory"); }
          else       { asm volatile("s_waitcnt vmcnt(0)" ::: "memory"); });
    // P2: kth1, mth0 — issue A1(t+1)
    PHASE(1, 0, if (!last) STG_A(nxt, t + 1, 1), );
    // P3: kth1, mth1 — issue B1(t+1); establish A0,B0 of t+1 (oldest 4)
    PHASE(1, 1, if (!last) STG_B(nxt, t + 1, 1),
          if (!last) { asm volatile("s_waitcnt vmcnt(4)" ::: "memory"); });
  }
#undef PHASE
#undef STG_A
#undef STG_B

  const int m0 = mt0 * 16, n0 = nf0 * 16;
#pragma unroll
  for (int ni = 0; ni < 4; ++ni) {
    int col = n0 + (wn + ni) * 16 + (l & 15);
    float bv = bias[col];
#pragma unroll
    for (int mi = 0; mi < 8; ++mi) {
#pragma unroll
      for (int q = 0; q < 4; ++q) {
        int row = m0 + (wm + mi) * 16 + ((l >> 4) << 2) + q;
        __builtin_nontemporal_store(acc[mi][ni][q] + bv, &C[(size_t)row * N + col]);
      }
    }
  }
}

// ---------- persistent GRU + overlapped Wout conversion: 256 blocks ----------
__launch_bounds__(768, 3)
__global__ void k_gru_persist(const u16* __restrict__ whh, const u16* __restrict__ whl,
                              const float* __restrict__ xcat, const float* __restrict__ bhr,
                              const float* __restrict__ bhz, const float* __restrict__ bhg,
                              const float* __restrict__ hinit, unsigned* __restrict__ hpack,
                              u16* __restrict__ hiddf, int* __restrict__ sync,
                              const float* __restrict__ Wout, u16* __restrict__ wof) {
  __shared__ unsigned hstage[16][1028];
  __shared__ float red[3][4][16][16];
  const int bid = (int)blockIdx.x;
  const int tid = threadIdx.x;

  if (bid >= 128) {
    // Wout converter: NT loads (no L3 pollution) + cached stores (wof -> L3)
    for (int g = (bid - 128) * 768 + tid; g < 4096000; g += 128 * 768) {
      int kt = g / 128000, rem = g - kt * 128000, nf = rem >> 6, l2 = rem & 63;
      int col = nf * 16 + (l2 & 15);
      int k0 = kt * 32 + ((l2 >> 4) << 3);
      u16 o[8];
#pragma unroll
      for (int e = 0; e < 8; ++e)
        o[e] = f2bf(__builtin_nontemporal_load(&Wout[(size_t)(k0 + e) * V_ + col]));
      *reinterpret_cast<uint4*>(wof + (size_t)g * 8) = *reinterpret_cast<const uint4*>(o);
    }
    return;
  }

  const int w = tid >> 6, l = tid & 63;
  const int mhalf = bid >> 6, jtile = bid & 63;
  const int gate = w >> 2, kg = w & 3;
  const int lr = l & 15, lc = (l >> 4) << 3;

  short8 bh[8], bl[8];
  {
    size_t wb = (size_t)(jtile * 3 + gate) * 32 * 512;
#pragma unroll
    for (int t = 0; t < 8; ++t) {
      size_t u = wb + ((size_t)(kg * 8 + t) * 64 + l) * 8;
      bh[t] = *reinterpret_cast<const short8*>(whh + u);
      bl[t] = *reinterpret_cast<const short8*>(whl + u);
    }
  }
#pragma unroll
  for (int t = 0; t < 8; ++t)
    asm volatile("" : "+v"(bh[t]), "+v"(bl[t]));

  const int erow = tid >> 4, ecol = tid & 15;
  const int eb = mhalf * 16 + erow, ej = jtile * 16 + ecol;
  const float* xp = xcat + (size_t)eb * S_ * 3072 + ej;
  float hprev = 0.f, br = 0.f, bz = 0.f, bg = 0.f, xr = 0.f, xz = 0.f, xg = 0.f;
  if (tid < 256) {
    hprev = hinit[(size_t)eb * H_ + ej];
    br = bhr[ej]; bz = bhz[ej]; bg = bhg[ej];
    xr = xp[0]; xz = xp[1024]; xg = xp[2048];
  }

  for (int s = 0; s < S_; ++s) {
    const int pi = s & 1, po = pi ^ 1;

    {
      const unsigned* hbase = hpack + (size_t)pi * (B_ * H_) + (size_t)(mhalf * 16) * H_;
      for (int c = w; c < 64; c += 12) {
        int r = c >> 2, q = c & 3;
        gload_lds16_sc(hbase + (size_t)r * H_ + q * 256 + l * 4, &hstage[r][q * 256]);
      }
    }
    __syncthreads();

    float nxr = 0.f, nxz = 0.f, nxg = 0.f;
    if (tid < 256 && s + 1 < S_) {
      const float* xq = xp + (size_t)(s + 1) * 3072;
      nxr = xq[0]; nxz = xq[1024]; nxg = xq[2048];
    }

    f32x4 acc = {};
#pragma unroll
    for (int t = 0; t < 8; ++t) {
      int c = (kg * 8 + t) * 32 + lc;
      uint4 A  = *reinterpret_cast<const uint4*>(&hstage[lr][c]);
      uint4 Bv = *reinterpret_cast<const uint4*>(&hstage[lr][c + 4]);
      union { unsigned u[4]; short8 s8; } ah, al;
      ah.u[0] = __builtin_amdgcn_perm(A.y, A.x, 0x05040100);
      al.u[0] = __builtin_amdgcn_perm(A.y, A.x, 0x07060302);
      ah.u[1] = __builtin_amdgcn_perm(A.w, A.z, 0x05040100);
      al.u[1] = __builtin_amdgcn_perm(A.w, A.z, 0x07060302);
      ah.u[2] = __builtin_amdgcn_perm(Bv.y, Bv.x, 0x05040100);
      al.u[2] = __builtin_amdgcn_perm(Bv.y, Bv.x, 0x07060302);
      ah.u[3] = __builtin_amdgcn_perm(Bv.w, Bv.z, 0x05040100);
      al.u[3] = __builtin_amdgcn_perm(Bv.w, Bv.z, 0x07060302);
      acc = __builtin_amdgcn_mfma_f32_16x16x32_bf16(ah.s8, bh[t], acc, 0, 0, 0);
      acc = __builtin_amdgcn_mfma_f32_16x16x32_bf16(ah.s8, bl[t], acc, 0, 0, 0);
      acc = __builtin_amdgcn_mfma_f32_16x16x32_bf16(al.s8, bh[t], acc, 0, 0, 0);
    }
#pragma unroll
    for (int q = 0; q < 4; ++q)
      red[gate][kg][(l >> 4) * 4 + q][lr] = acc[q];
    __syncthreads();

    if (tid < 256) {
      float ar = br + xr, az = bz + xz, ag = bg;
#pragma unroll
      for (int k2 = 0; k2 < 4; ++k2) {
        ar += red[0][k2][erow][ecol];
        az += red[1][k2][erow][ecol];
        ag += red[2][k2][erow][ecol];
      }
      float r = 1.f / (1.f + __expf(-ar));
      float z = 1.f / (1.f + __expf(-az));
      float ta = xg + r * ag;
      float gv = 1.f - 2.f / (__expf(2.f * ta) + 1.f);  // tanh
      float hnew = (1.f - z) * gv + z * hprev;
      hprev = hnew;
      u16 hi = f2bf(hnew);
      u16 lo = f2bf(hnew - bf2f(hi));
      __hip_atomic_store(hpack + (size_t)po * (B_ * H_) + (size_t)eb * H_ + ej,
                         (unsigned)hi | ((unsigned)lo << 16),
                         __ATOMIC_RELAXED, __HIP_MEMORY_SCOPE_AGENT);
      int row = eb * S_ + s;
      int ktO = ej >> 5, mtO = row >> 4, laneO = (row & 15) + 16 * ((ej >> 3) & 3);
      hiddf[(((size_t)ktO * 256 + mtO) * 64 + laneO) * 8 + (ej & 7)] = hi;
    }
    xr = nxr; xz = nxz; xg = nxg;

    if (s + 1 < S_) {
      __syncthreads();
      if (tid == 0)
        __hip_atomic_store(sync + bid * 16, s + 1,
                           __ATOMIC_RELAXED, __HIP_MEMORY_SCOPE_AGENT);
      if (tid < 64) {
        const int* fp = sync + (mhalf * 64 + tid) * 16;
        while (__hip_atomic_load(fp, __ATOMIC_RELAXED, __HIP_MEMORY_SCOPE_AGENT) <= s)
          __builtin_amdgcn_s_sleep(1);
      }
      __syncthreads();
    }
  }
}

extern "C" void kernel_launch(void* const* d_in, const int* in_sizes, int n_in,
                              void* d_out, int out_size, void* d_ws, size_t ws_size,
                              hipStream_t stream) {
  const int*   inputs      = (const int*)d_in[0];
  const float* hidden_init = (const float*)d_in[2];
  const float* E    = (const float*)d_in[3];
  const float* Wxr  = (const float*)d_in[4];  const float* bxr = (const float*)d_in[5];
  const float* Wxz  = (const float*)d_in[6];  const float* bxz = (const float*)d_in[7];
  const float* Wxg  = (const float*)d_in[8];  const float* bxg = (const float*)d_in[9];
  const float* Whr  = (const float*)d_in[10]; const float* bhr = (const float*)d_in[11];
  const float* Whz  = (const float*)d_in[12]; const float* bhz = (const float*)d_in[13];
  const float* Whg  = (const float*)d_in[14]; const float* bhg = (const float*)d_in[15];
  const float* Wout = (const float*)d_in[16]; const float* bout = (const float*)d_in[17];
  float* out = (float*)d_out;

  char* ws = (char*)d_ws;
  u16* wxf       = (u16*)(ws);                  //  6,291,456
  u16* wof       = (u16*)(ws + 6291456);        // 65,536,000
  u16* embf      = (u16*)(ws + 71827456);       //  8,388,608 (aliased: hiddf after xproj)
  u16* hiddf     = embf;                        //  alias — emb fully consumed by xproj first
  float* bcat    = (float*)(ws + 80216064);     //     12,288
  float* xcat    = (float*)(ws + 80228352);     // 50,331,648
  u16* whh       = (u16*)(ws + 130560000);      //  6,291,456
  u16* whl       = (u16*)(ws + 136851456);      //  6,291,456
  unsigned* hpack= (unsigned*)(ws + 143142912); //    262,144 (2 slots x 32x1024 u32)
  int* syncb     = (int*)(ws + 143405056);      //     32,768 (flag barrier state)

  // all prep conversions in one launch
  k_prep_all<<<5261, 256, 0, stream>>>(inputs, E, embf, Wxr, Wxz, Wxg, wxf,
                                       Whr, Whz, Whg, whh, whl,
                                       hidden_init, hpack, syncb,
                                       bxr, bxz, bxg, bcat);

  // x-projections: [4096][3072] fp32 (m97 structure — better grid fill at N=3072)
  k_gemm_frag<0><<<dim3(32, 24), 256, 0, stream>>>(embf, wxf, bcat, xcat, 256, 192, 32, 3072);

  // recurrence (blocks 0-127) + overlapped Wout conversion (blocks 128-255)
  {
    const u16* whh_p = whh; const u16* whl_p = whl; const float* xcat_p = xcat;
    const float* bhr_p = bhr; const float* bhz_p = bhz; const float* bhg_p = bhg;
    const float* hinit_p = hidden_init; unsigned* hpack_p = hpack;
    u16* hiddf_p = hiddf; int* sync_p = syncb;
    const float* wout_p = Wout; u16* wof_p = wof;
    void* kargs[] = {&whh_p, &whl_p, &xcat_p, &bhr_p, &bhz_p, &bhg_p,
                     &hinit_p, &hpack_p, &hiddf_p, &sync_p, &wout_p, &wof_p};
    hipLaunchCooperativeKernel((const void*)k_gru_persist, dim3(256), dim3(768),
                               kargs, 0, stream);
  }

  // output: [4096][32000] fp32 — 256x256 pipelined GEMM, NT C stores
  k_gemm256p<<<dim3(16, 125), 512, 0, stream>>>(hiddf, wof, bout, out, 256, 2000, 16, 32000);
}

// Round 17
// 740.475 us; speedup vs baseline: 1.0943x; 1.0943x over previous
//
#include <hip/hip_runtime.h>
#include <hip/hip_bf16.h>

#define B_ 32
#define S_ 128
#define H_ 1024
#define V_ 32000

using short8 = __attribute__((ext_vector_type(8))) short;
using f32x4  = __attribute__((ext_vector_type(4))) float;
using u32x4  = __attribute__((ext_vector_type(4))) unsigned;
typedef unsigned short u16;

__device__ inline u16 f2bf(float f) {
  unsigned u = __float_as_uint(f);
  unsigned r = u + 0x7FFFu + ((u >> 16) & 1u);  // RNE
  return (u16)(r >> 16);
}
__device__ inline float bf2f(u16 h) { return __uint_as_float(((unsigned)h) << 16); }

__device__ inline void gload_lds16(const void* g, void* l) {
  __builtin_amdgcn_global_load_lds((const __attribute__((address_space(1))) unsigned int*)g,
                                   (__attribute__((address_space(3))) unsigned int*)l, 16, 0, 0);
}
// sc0|sc1 (CPol GLC|SCC = 17): bypass L1/L2, fetch from coherence point — same
// visibility semantics as agent-scope atomic loads, but async + zero VGPRs.
__device__ inline void gload_lds16_sc(const void* g, void* l) {
  __builtin_amdgcn_global_load_lds((const __attribute__((address_space(1))) unsigned int*)g,
                                   (__attribute__((address_space(3))) unsigned int*)l, 16, 0, 17);
}

// ---- A-frag layout: unit(kt, mt, l) = (kt*MT + mt)*64 + l ; 8 bf16 per unit ----
// element: row = mt*16 + (l&15), k = kt*32 + (l>>4)*8 + j
// ---- B-frag layout: unit(kt, nf, l) = (kt*NT + nf)*64 + l ----

// ---------- merged prep: all conversions in one launch (region-dispatched) ----------
__global__ void k_prep_all(const int* __restrict__ idx, const float* __restrict__ E,
                           u16* __restrict__ embf,
                           const float* __restrict__ Wxr, const float* __restrict__ Wxz,
                           const float* __restrict__ Wxg, u16* __restrict__ wxf,
                           const float* __restrict__ Whr, const float* __restrict__ Whz,
                           const float* __restrict__ Whg, u16* __restrict__ whh,
                           u16* __restrict__ whl,
                           const float* __restrict__ h0, unsigned* __restrict__ hpack,
                           int* __restrict__ sync,
                           const float* __restrict__ bxr, const float* __restrict__ bxz,
                           const float* __restrict__ bxg, float* __restrict__ bcat) {
  int gg = blockIdx.x * blockDim.x + threadIdx.x;
  if (gg < 524288) {
    int g = gg;
    int kt = g >> 14, rem = g & 16383, mt = rem >> 6, l = rem & 63;
    int row = mt * 16 + (l & 15);
    int k = kt * 32 + ((l >> 4) << 3);
    const float4* src = reinterpret_cast<const float4*>(E + (size_t)idx[row] * H_ + k);
    float4 a = src[0], b = src[1];
    u16 o[8] = {f2bf(a.x), f2bf(a.y), f2bf(a.z), f2bf(a.w),
                f2bf(b.x), f2bf(b.y), f2bf(b.z), f2bf(b.w)};
    *reinterpret_cast<uint4*>(embf + (size_t)g * 8) = *reinterpret_cast<const uint4*>(o);
  } else if (gg < 917504) {
    int g = gg - 524288;
    int kt = g / 12288, rem = g % 12288, nf = rem >> 6, l = rem & 63;
    int col = nf * 16 + (l & 15);
    int gate = col >> 10, j = col & 1023;
    int k0 = kt * 32 + ((l >> 4) << 3);
    const float* W = gate == 0 ? Wxr : (gate == 1 ? Wxz : Wxg);
    u16 o[8];
#pragma unroll
    for (int e = 0; e < 8; ++e) o[e] = f2bf(W[(size_t)(k0 + e) * H_ + j]);
    *reinterpret_cast<uint4*>(wxf + (size_t)g * 8) = *reinterpret_cast<const uint4*>(o);
  } else if (gg < 1310720) {
    int g = gg - 917504;
    int jtile = g / 6144, rem = g % 6144;
    int gate = rem >> 11, kt = (rem >> 6) & 31, l = rem & 63;
    int col = jtile * 16 + (l & 15);
    int k0 = kt * 32 + ((l >> 4) << 3);
    const float* W = gate == 0 ? Whr : (gate == 1 ? Whz : Whg);
    u16 oh[8], ol[8];
#pragma unroll
    for (int e = 0; e < 8; ++e) {
      float v = W[(size_t)(k0 + e) * H_ + col];
      u16 hi = f2bf(v);
      oh[e] = hi;
      ol[e] = f2bf(v - bf2f(hi));
    }
    *reinterpret_cast<uint4*>(whh + (size_t)g * 8) = *reinterpret_cast<const uint4*>(oh);
    *reinterpret_cast<uint4*>(whl + (size_t)g * 8) = *reinterpret_cast<const uint4*>(ol);
  } else if (gg < 1343488) {
    int i = gg - 1310720;
    float v = h0[i];
    u16 hi = f2bf(v);
    hpack[i] = (unsigned)hi | ((unsigned)f2bf(v - bf2f(hi)) << 16);
    if (i < 8192) sync[i] = 0;
  } else if (gg < 1346560) {
    int j = gg - 1343488;
    bcat[j] = j < 1024 ? bxr[j] : (j < 2048 ? bxz[j - 1024] : bxg[j - 2048]);
  }
}

// ---------- m97-style GEMM on frag-order inputs: C[M][N] = A*B + bias ----------
// grid: (MT/8, NT/8) — mt varies FASTEST so concurrent blocks share one B-panel.
// NT=1: nontemporal C stores (bypass L2/L3) keep A/B panels L3-resident.
// 3 blocks/CU (96KB LDS): 12 waves/CU hide the per-K-tile barrier drain.
template <int NTSTORE>
__launch_bounds__(256, 3)
__global__ void k_gemm_frag(const u16* __restrict__ Af, const u16* __restrict__ Bf,
                            const float* __restrict__ bias, float* __restrict__ C,
                            int MT, int NT, int KT, int N) {
  __shared__ __align__(16) u16 lA[2 * 512 * 8];
  __shared__ __align__(16) u16 lB[2 * 512 * 8];
  int tid = threadIdx.x, w = tid >> 6, lane = tid & 63;
  int mt0 = blockIdx.x * 8, nf0 = blockIdx.y * 8;
  int wm = (w >> 1) * 4, wn = (w & 1) * 4;
  f32x4 acc[4][4] = {};
  for (int kt = 0; kt < KT; kt += 2) {
    __syncthreads();
#pragma unroll
    for (int hh = 0; hh < 2; ++hh) {
      const u16* ga = Af + ((size_t)(kt + hh) * MT + mt0) * 512;
      const u16* gb = Bf + ((size_t)(kt + hh) * NT + nf0) * 512;
#pragma unroll
      for (int r = 0; r < 2; ++r) {
        int ub = (r * 4 + w) * 64;
        gload_lds16(ga + (size_t)(ub + lane) * 8, lA + (size_t)(hh * 512 + ub) * 8);
        gload_lds16(gb + (size_t)(ub + lane) * 8, lB + (size_t)(hh * 512 + ub) * 8);
      }
    }
    __syncthreads();
#pragma unroll
    for (int hh = 0; hh < 2; ++hh) {
      short8 af[4], bfr[4];
#pragma unroll
      for (int i = 0; i < 4; ++i) {
        af[i]  = *reinterpret_cast<const short8*>(lA + ((hh * 8 + wm + i) * 64 + lane) * 8);
        bfr[i] = *reinterpret_cast<const short8*>(lB + ((hh * 8 + wn + i) * 64 + lane) * 8);
      }
#pragma unroll
      for (int mi = 0; mi < 4; ++mi)
#pragma unroll
        for (int ni = 0; ni < 4; ++ni)
          acc[mi][ni] = __builtin_amdgcn_mfma_f32_16x16x32_bf16(af[mi], bfr[ni], acc[mi][ni], 0, 0, 0);
    }
  }
  int m0 = mt0 * 16, n0 = nf0 * 16;
#pragma unroll
  for (int ni = 0; ni < 4; ++ni) {
    int col = n0 + (wn + ni) * 16 + (lane & 15);
    float bv = bias[col];
#pragma unroll
    for (int mi = 0; mi < 4; ++mi) {
#pragma unroll
      for (int q = 0; q < 4; ++q) {
        int row = m0 + (wm + mi) * 16 + ((lane >> 4) << 2) + q;
        float v = acc[mi][ni][q] + bv;
        if (NTSTORE) __builtin_nontemporal_store(v, &C[(size_t)row * N + col]);
        else         C[(size_t)row * N + col] = v;
      }
    }
  }
}

// ---------- persistent GRU + overlapped Wout conversion: 256 blocks ----------
// blocks 0-127: producer (flag barrier among themselves only).
// blocks 128-255: Wout fp32->bf16 conversion — NT LOADS (the 130MB read stream
// doesn't pollute L3) + CACHED stores (wof lands in L2, flushed to L3 at kernel
// end, so the output GEMM finds its B-matrix L3-resident).
__launch_bounds__(768, 3)
__global__ void k_gru_persist(const u16* __restrict__ whh, const u16* __restrict__ whl,
                              const float* __restrict__ xcat, const float* __restrict__ bhr,
                              const float* __restrict__ bhz, const float* __restrict__ bhg,
                              const float* __restrict__ hinit, unsigned* __restrict__ hpack,
                              u16* __restrict__ hiddf, int* __restrict__ sync,
                              const float* __restrict__ Wout, u16* __restrict__ wof) {
  __shared__ unsigned hstage[16][1028];   // 16 h-rows x 1024 packed u32 (pad for banks)
  __shared__ float red[3][4][16][16];
  const int bid = (int)blockIdx.x;
  const int tid = threadIdx.x;

  if (bid >= 128) {
    // ---- Wout converter: 4,096,000 units, grid-stride; NT load + cached store ----
    for (int g = (bid - 128) * 768 + tid; g < 4096000; g += 128 * 768) {
      int kt = g / 128000, rem = g - kt * 128000, nf = rem >> 6, l2 = rem & 63;
      int col = nf * 16 + (l2 & 15);
      int k0 = kt * 32 + ((l2 >> 4) << 3);
      u16 o[8];
#pragma unroll
      for (int e = 0; e < 8; ++e)
        o[e] = f2bf(__builtin_nontemporal_load(&Wout[(size_t)(k0 + e) * V_ + col]));
      *reinterpret_cast<uint4*>(wof + (size_t)g * 8) = *reinterpret_cast<const uint4*>(o);
    }
    return;
  }

  const int w = tid >> 6, l = tid & 63;
  const int mhalf = bid >> 6, jtile = bid & 63;
  const int gate = w >> 2, kg = w & 3;
  const int lr = l & 15, lc = (l >> 4) << 3;

  // hidden->hidden weights resident in VGPRs (hi/lo bf16 split): 64 VGPR/thread
  short8 bh[8], bl[8];
  {
    size_t wb = (size_t)(jtile * 3 + gate) * 32 * 512;
#pragma unroll
    for (int t = 0; t < 8; ++t) {
      size_t u = wb + ((size_t)(kg * 8 + t) * 64 + l) * 8;
      bh[t] = *reinterpret_cast<const short8*>(whh + u);
      bl[t] = *reinterpret_cast<const short8*>(whl + u);
    }
  }
#pragma unroll
  for (int t = 0; t < 8; ++t)
    asm volatile("" : "+v"(bh[t]), "+v"(bl[t]));

  // epilogue thread state (tid < 256): one (b, j) output element
  const int erow = tid >> 4, ecol = tid & 15;
  const int eb = mhalf * 16 + erow, ej = jtile * 16 + ecol;
  const float* xp = xcat + (size_t)eb * S_ * 3072 + ej;
  float hprev = 0.f, br = 0.f, bz = 0.f, bg = 0.f, xr = 0.f, xz = 0.f, xg = 0.f;
  if (tid < 256) {
    hprev = hinit[(size_t)eb * H_ + ej];
    br = bhr[ej]; bz = bhz[ej]; bg = bhg[ej];
    xr = xp[0]; xz = xp[1024]; xg = xp[2048];
  }

  for (int s = 0; s < S_; ++s) {
    const int pi = s & 1, po = pi ^ 1;

    // ---- stage h into LDS: 64 async 1KB DMA chunks (sc0|sc1, L2-bypass) ----
    {
      const unsigned* hbase = hpack + (size_t)pi * (B_ * H_) + (size_t)(mhalf * 16) * H_;
      for (int c = w; c < 64; c += 12) {
        int r = c >> 2, q = c & 3;
        gload_lds16_sc(hbase + (size_t)r * H_ + q * 256 + l * 4, &hstage[r][q * 256]);
      }
    }
    __syncthreads();  // vmcnt(0): all DMA chunks landed

    // early prefetch of next step's x operands (drains under MFMA+epilogue)
    float nxr = 0.f, nxz = 0.f, nxg = 0.f;
    if (tid < 256 && s + 1 < S_) {
      const float* xq = xp + (size_t)(s + 1) * 3072;
      nxr = xq[0]; nxz = xq[1024]; nxg = xq[2048];
    }

    // ---- fragment assembly (b128 + v_perm) + MFMA (weights in VGPRs) ----
    f32x4 acc = {};
#pragma unroll
    for (int t = 0; t < 8; ++t) {
      int c = (kg * 8 + t) * 32 + lc;
      uint4 A  = *reinterpret_cast<const uint4*>(&hstage[lr][c]);
      uint4 Bv = *reinterpret_cast<const uint4*>(&hstage[lr][c + 4]);
      union { unsigned u[4]; short8 s8; } ah, al;
      ah.u[0] = __builtin_amdgcn_perm(A.y, A.x, 0x05040100);
      al.u[0] = __builtin_amdgcn_perm(A.y, A.x, 0x07060302);
      ah.u[1] = __builtin_amdgcn_perm(A.w, A.z, 0x05040100);
      al.u[1] = __builtin_amdgcn_perm(A.w, A.z, 0x07060302);
      ah.u[2] = __builtin_amdgcn_perm(Bv.y, Bv.x, 0x05040100);
      al.u[2] = __builtin_amdgcn_perm(Bv.y, Bv.x, 0x07060302);
      ah.u[3] = __builtin_amdgcn_perm(Bv.w, Bv.z, 0x05040100);
      al.u[3] = __builtin_amdgcn_perm(Bv.w, Bv.z, 0x07060302);
      acc = __builtin_amdgcn_mfma_f32_16x16x32_bf16(ah.s8, bh[t], acc, 0, 0, 0);
      acc = __builtin_amdgcn_mfma_f32_16x16x32_bf16(ah.s8, bl[t], acc, 0, 0, 0);
      acc = __builtin_amdgcn_mfma_f32_16x16x32_bf16(al.s8, bh[t], acc, 0, 0, 0);
    }
#pragma unroll
    for (int q = 0; q < 4; ++q)
      red[gate][kg][(l >> 4) * 4 + q][lr] = acc[q];
    __syncthreads();

    // ---- epilogue ----
    if (tid < 256) {
      float ar = br + xr, az = bz + xz, ag = bg;
#pragma unroll
      for (int k2 = 0; k2 < 4; ++k2) {
        ar += red[0][k2][erow][ecol];
        az += red[1][k2][erow][ecol];
        ag += red[2][k2][erow][ecol];
      }
      float r = 1.f / (1.f + __expf(-ar));
      float z = 1.f / (1.f + __expf(-az));
      float ta = xg + r * ag;
      float gv = 1.f - 2.f / (__expf(2.f * ta) + 1.f);  // tanh
      float hnew = (1.f - z) * gv + z * hprev;
      hprev = hnew;
      u16 hi = f2bf(hnew);
      u16 lo = f2bf(hnew - bf2f(hi));
      // write-through h (crosses the barrier)
      __hip_atomic_store(hpack + (size_t)po * (B_ * H_) + (size_t)eb * H_ + ej,
                         (unsigned)hi | ((unsigned)lo << 16),
                         __ATOMIC_RELAXED, __HIP_MEMORY_SCOPE_AGENT);
      // hiddf (consumed after kernel end; plain cached store is fine)
      int row = eb * S_ + s;
      int ktO = ej >> 5, mtO = row >> 4, laneO = (row & 15) + 16 * ((ej >> 3) & 3);
      hiddf[(((size_t)ktO * 256 + mtO) * 64 + laneO) * 8 + (ej & 7)] = hi;
    }
    xr = nxr; xz = nxz; xg = nxg;

    if (s + 1 < S_) {
      // distributed flag barrier among the 64 blocks sharing mhalf.
      // __syncthreads drains all vmem (incl. agent h stores) before arrival.
      __syncthreads();
      if (tid == 0)
        __hip_atomic_store(sync + bid * 16, s + 1,
                           __ATOMIC_RELAXED, __HIP_MEMORY_SCOPE_AGENT);
      if (tid < 64) {
        const int* fp = sync + (mhalf * 64 + tid) * 16;
        while (__hip_atomic_load(fp, __ATOMIC_RELAXED, __HIP_MEMORY_SCOPE_AGENT) <= s)
          __builtin_amdgcn_s_sleep(1);
      }
      __syncthreads();
    }
  }
}

extern "C" void kernel_launch(void* const* d_in, const int* in_sizes, int n_in,
                              void* d_out, int out_size, void* d_ws, size_t ws_size,
                              hipStream_t stream) {
  const int*   inputs      = (const int*)d_in[0];
  const float* hidden_init = (const float*)d_in[2];
  const float* E    = (const float*)d_in[3];
  const float* Wxr  = (const float*)d_in[4];  const float* bxr = (const float*)d_in[5];
  const float* Wxz  = (const float*)d_in[6];  const float* bxz = (const float*)d_in[7];
  const float* Wxg  = (const float*)d_in[8];  const float* bxg = (const float*)d_in[9];
  const float* Whr  = (const float*)d_in[10]; const float* bhr = (const float*)d_in[11];
  const float* Whz  = (const float*)d_in[12]; const float* bhz = (const float*)d_in[13];
  const float* Whg  = (const float*)d_in[14]; const float* bhg = (const float*)d_in[15];
  const float* Wout = (const float*)d_in[16]; const float* bout = (const float*)d_in[17];
  float* out = (float*)d_out;

  char* ws = (char*)d_ws;
  u16* wxf       = (u16*)(ws);                  //  6,291,456
  u16* wof       = (u16*)(ws + 6291456);        // 65,536,000
  u16* embf      = (u16*)(ws + 71827456);       //  8,388,608 (aliased: hiddf after xproj)
  u16* hiddf     = embf;                        //  alias — emb fully consumed by xproj first
  float* bcat    = (float*)(ws + 80216064);     //     12,288
  float* xcat    = (float*)(ws + 80228352);     // 50,331,648
  u16* whh       = (u16*)(ws + 130560000);      //  6,291,456
  u16* whl       = (u16*)(ws + 136851456);      //  6,291,456
  unsigned* hpack= (unsigned*)(ws + 143142912); //    262,144 (2 slots x 32x1024 u32)
  int* syncb     = (int*)(ws + 143405056);      //     32,768 (flag barrier state)

  // all prep conversions in one launch (1,346,560 units / 256)
  k_prep_all<<<5261, 256, 0, stream>>>(inputs, E, embf, Wxr, Wxz, Wxg, wxf,
                                       Whr, Whz, Whg, whh, whl,
                                       hidden_init, hpack, syncb,
                                       bxr, bxz, bxg, bcat);

  // x-projections: [4096][3072] fp32 (mt fastest; cached stores — read back by gru)
  k_gemm_frag<0><<<dim3(32, 24), 256, 0, stream>>>(embf, wxf, bcat, xcat, 256, 192, 32, 3072);

  // recurrence (blocks 0-127) + overlapped Wout conversion (blocks 128-255)
  {
    const u16* whh_p = whh; const u16* whl_p = whl; const float* xcat_p = xcat;
    const float* bhr_p = bhr; const float* bhz_p = bhz; const float* bhg_p = bhg;
    const float* hinit_p = hidden_init; unsigned* hpack_p = hpack;
    u16* hiddf_p = hiddf; int* sync_p = syncb;
    const float* wout_p = Wout; u16* wof_p = wof;
    void* kargs[] = {&whh_p, &whl_p, &xcat_p, &bhr_p, &bhz_p, &bhg_p,
                     &hinit_p, &hpack_p, &hiddf_p, &sync_p, &wout_p, &wof_p};
    hipLaunchCooperativeKernel((const void*)k_gru_persist, dim3(256), dim3(768),
                               kargs, 0, stream);
  }

  // output: [4096][32000] fp32 — NONTEMPORAL C stores keep A/B L3-resident
  k_gemm_frag<1><<<dim3(32, 250), 256, 0, stream>>>(hiddf, wof, bout, out, 256, 2000, 32, 32000);
}